// Round 4
// baseline (397.795 us; speedup 1.0000x reference)
//
#include <hip/hip_runtime.h>
#include <hip/hip_bf16.h>
#include <cstdint>
#include <cstddef>

#define S 2048
#define D 4096
#define H 32
#define G 8
#define DH 128
#define HD (H*DH)   // 4096
#define GD (G*DH)   // 1024

typedef __bf16 bf16;
typedef __bf16 bf16x4 __attribute__((ext_vector_type(4)));
typedef __bf16 bf16x8 __attribute__((ext_vector_type(8)));
typedef float f32x4 __attribute__((ext_vector_type(4)));

__device__ __forceinline__ void gload16(const void* g, void* l) {
    __builtin_amdgcn_global_load_lds(
        (const __attribute__((address_space(1))) void*)g,
        (__attribute__((address_space(3))) void*)l, 16, 0, 0);
}

#define FENCE() asm volatile("" ::: "memory")
#define BARRIER() do { FENCE(); __builtin_amdgcn_s_barrier(); FENCE(); } while (0)
#define LGKM0()  do { asm volatile("s_waitcnt lgkmcnt(0)" ::: "memory"); \
                      __builtin_amdgcn_sched_barrier(0); } while (0)
#define VMCNT(n) asm volatile("s_waitcnt vmcnt(" #n ")" ::: "memory")

// ---------------------------------------------------------------- cast x -> bf16
__global__ __launch_bounds__(256) void cast_f32_bf16(const float* __restrict__ in,
                                                     bf16* __restrict__ out, int n4)
{
    int i = blockIdx.x * 256 + threadIdx.x;
    if (i < n4) {
        float4 v = reinterpret_cast<const float4*>(in)[i];
        bf16x4 o = { (bf16)v.x, (bf16)v.y, (bf16)v.z, (bf16)v.w };
        reinterpret_cast<bf16x4*>(out)[i] = o;
    }
}

// ---------------------------------------------------------------- transpose -> bf16
template<bool IN_F32>
__global__ __launch_bounds__(256) void transpose_to_bf16(
    const void* __restrict__ in, bf16* __restrict__ out, int R, int C)
{
    const int cb = threadIdx.x & 63, rb = threadIdx.x >> 6;
    const int c0 = blockIdx.x * 512 + cb * 8;
    const int r0 = blockIdx.y * 32 + rb * 8;
    bf16 m[8][8];
    #pragma unroll
    for (int j = 0; j < 8; ++j) {
        if constexpr (IN_F32) {
            const float* p = (const float*)in + (size_t)(r0 + j) * C + c0;
            float4 a = *reinterpret_cast<const float4*>(p);
            float4 b = *reinterpret_cast<const float4*>(p + 4);
            m[j][0] = (bf16)a.x; m[j][1] = (bf16)a.y; m[j][2] = (bf16)a.z; m[j][3] = (bf16)a.w;
            m[j][4] = (bf16)b.x; m[j][5] = (bf16)b.y; m[j][6] = (bf16)b.z; m[j][7] = (bf16)b.w;
        } else {
            const bf16* p = (const bf16*)in + (size_t)(r0 + j) * C + c0;
            bf16x8 v = *reinterpret_cast<const bf16x8*>(p);
            #pragma unroll
            for (int i = 0; i < 8; ++i) m[j][i] = v[i];
        }
    }
    #pragma unroll
    for (int i = 0; i < 8; ++i) {
        bf16x8 ov;
        #pragma unroll
        for (int j = 0; j < 8; ++j) ov[j] = m[j][i];
        *reinterpret_cast<bf16x8*>(out + (size_t)(c0 + i) * R + r0) = ov;
    }
}

// ---------------------------------------------------------------- RoPE in-place (+scale)
__global__ __launch_bounds__(256) void rope_inplace(bf16* __restrict__ Y,
                                                    const float* __restrict__ cosT,
                                                    const float* __restrict__ sinT,
                                                    int ncols, int total, float scale)
{
    int idx = blockIdx.x * 256 + threadIdx.x;
    if (idx >= total) return;
    int pairs = ncols >> 1;
    int s = idx / pairs;
    int p = idx - s * pairs;
    int head = p >> 6;
    int d = p & 63;
    size_t base = (size_t)s * ncols + head * DH;
    float c  = cosT[s * DH + d];
    float sn = sinT[s * DH + d];
    float a = (float)Y[base + d];
    float b = (float)Y[base + d + 64];
    Y[base + d]      = (bf16)((a * c - b * sn) * scale);
    Y[base + d + 64] = (bf16)((b * c + a * sn) * scale);
}

// ================================================================ 8-phase 256x256 GEMM
// C[M,N] = A[M,K](bf16) * Bt[N,K](bf16). BK=64, 2 LDS buffers (64KB each),
// 8 waves (2M x 4N, per-wave 128x64). Derived race-free stage schedule:
//   per iter (tiles a=2j buf0 ph1-4, b=2j+1 buf1 ph5-8):
//   ph1:Ah'1(b) ph2:Bh0(b) ph3:Bh1(b) ph4:Ah'0(c)+vmcnt(2)
//   ph5:Ah'1(c) ph6:Bh0(c) ph7:Bh1(c) ph8:Ah'0(d)+vmcnt(2)
// where c=2j+2->buf0, d=2j+3->buf1; A-halves interleaved {h*64+[0,64)}u{128+h*64+[0,64)}
// matching mh-quad retirement. B frags register-cached across the 4 phases of a tile.
// Swizzle: LDS chunk c holds global chunk c^(row&7); reads use (ks*4+lhi)^(l15&7).

#define EPI_QKV 0
#define EPI_F32 1

template<int EPI>
__global__ __launch_bounds__(512) void gemm8p(
    const bf16* __restrict__ A, const bf16* __restrict__ Bt,
    void* __restrict__ C, bf16* __restrict__ Kout, bf16* __restrict__ Vout,
    int N, int K, int nbn)
{
    extern __shared__ char smem[];   // buf d: A @ d*65536, B @ d*65536+32768
    const int tid = threadIdx.x, lane = tid & 63, wave = tid >> 6;
    const int wr = wave >> 2, wc = wave & 3;
    const int l15 = lane & 15, lhi = lane >> 4;
    const int r8 = lane >> 3, c8 = lane & 7;
    const int csw = ((c8 ^ r8) << 3);          // pre-swizzled source chunk (elems)

    const int nwg = gridDim.x, qq = nwg >> 3;
    const int swz = (blockIdx.x & 7) * qq + (blockIdx.x >> 3);
    const int bm = (swz / nbn) * 256, bn = (swz % nbn) * 256;
    const int NT = K >> 6;

    auto stageA = [&](int buf, int h, int t) {
        #pragma unroll
        for (int L = 0; L < 2; ++L) {
            int row0 = L * 128 + h * 64 + wave * 8;
            gload16(A + (size_t)(bm + row0 + r8) * K + (t << 6) + csw,
                    smem + buf * 65536 + row0 * 128);
        }
    };
    auto stageB = [&](int buf, int h, int t) {
        #pragma unroll
        for (int L = 0; L < 2; ++L) {
            int row0 = h * 128 + L * 64 + wave * 8;
            gload16(Bt + (size_t)(bn + row0 + r8) * K + (t << 6) + csw,
                    smem + buf * 65536 + 32768 + row0 * 128);
        }
    };
    auto rdA = [&](const char* Ab, int mh, int ks, bf16x8* af) {
        #pragma unroll
        for (int m = 0; m < 4; ++m) {
            int row = wr * 128 + mh * 64 + m * 16 + l15;
            int ch = (ks * 4 + lhi) ^ (l15 & 7);
            af[m] = *reinterpret_cast<const bf16x8*>(Ab + row * 128 + ch * 16);
        }
    };
    auto rdB = [&](const char* Bb, int ks, bf16x8* bfv) {
        #pragma unroll
        for (int n = 0; n < 4; ++n) {
            int row = wc * 64 + n * 16 + l15;
            int ch = (ks * 4 + lhi) ^ (l15 & 7);
            bfv[n] = *reinterpret_cast<const bf16x8*>(Bb + row * 128 + ch * 16);
        }
    };

    f32x4 acc[8][4] = {};

    auto mm = [&](int mh, const bf16x8* af, const bf16x8* bfv) {
        LGKM0();
        __builtin_amdgcn_s_setprio(1);
        #pragma unroll
        for (int m = 0; m < 4; ++m)
            #pragma unroll
            for (int n = 0; n < 4; ++n)
                acc[mh * 4 + m][n] = __builtin_amdgcn_mfma_f32_16x16x32_bf16(
                    af[m], bfv[n], acc[mh * 4 + m][n], 0, 0, 0);
        __builtin_amdgcn_s_setprio(0);
    };

    // prologue: tile0 -> buf0 (all 4 units) + Ah'0(tile1) -> buf1
    stageA(0, 0, 0); stageA(0, 1, 0); stageB(0, 0, 0); stageB(0, 1, 0);
    stageA(1, 0, 1);
    VMCNT(2);
    BARRIER();

    const char* A0 = smem;
    const char* B0 = smem + 32768;
    const char* A1 = smem + 65536;
    const char* B1 = smem + 65536 + 32768;

    for (int j = 0; j < (NT >> 1); ++j) {
        const int tb = 2 * j + 1;
        const int t2 = (2 * j + 2 < NT) ? 2 * j + 2 : NT - 1;
        const int t3 = (2 * j + 3 < NT) ? 2 * j + 3 : NT - 1;
        bf16x8 af[4], bk0[4], bk1[4];

        // ---- tile a (buf0)
        rdB(B0, 0, bk0); rdA(A0, 0, 0, af);
        stageA(1, 1, tb);
        mm(0, af, bk0);
        BARRIER();

        rdB(B0, 1, bk1); rdA(A0, 0, 1, af);
        stageB(1, 0, tb);
        mm(0, af, bk1);
        BARRIER();

        rdA(A0, 1, 0, af);
        stageB(1, 1, tb);
        mm(1, af, bk0);
        BARRIER();

        rdA(A0, 1, 1, af);
        stageA(0, 0, t2);
        VMCNT(2);                    // tile b fully landed (allows ph4's own 2)
        mm(1, af, bk1);
        BARRIER();

        // ---- tile b (buf1)
        rdB(B1, 0, bk0); rdA(A1, 0, 0, af);
        stageA(0, 1, t2);
        mm(0, af, bk0);
        BARRIER();

        rdB(B1, 1, bk1); rdA(A1, 0, 1, af);
        stageB(0, 0, t2);
        mm(0, af, bk1);
        BARRIER();

        rdA(A1, 1, 0, af);
        stageB(0, 1, t2);
        mm(1, af, bk0);
        BARRIER();

        rdA(A1, 1, 1, af);
        stageA(1, 0, t3);
        VMCNT(2);                    // tile t2 fully landed
        mm(1, af, bk1);
        BARRIER();
    }

    #pragma unroll
    for (int m = 0; m < 8; ++m) {
        int r0 = bm + wr * 128 + m * 16 + lhi * 4;
        #pragma unroll
        for (int n = 0; n < 4; ++n) {
            int c = bn + wc * 64 + n * 16 + l15;
            #pragma unroll
            for (int j = 0; j < 4; ++j) {
                if constexpr (EPI == EPI_F32) {
                    reinterpret_cast<float*>(C)[(size_t)(r0 + j) * N + c] = acc[m][n][j];
                } else {
                    if (bn < HD)
                        reinterpret_cast<bf16*>(C)[(size_t)(r0 + j) * HD + c] = (bf16)acc[m][n][j];
                    else if (bn < HD + GD)
                        Kout[(size_t)(r0 + j) * GD + (c - HD)] = (bf16)acc[m][n][j];
                    else
                        Vout[(size_t)(r0 + j) * GD + (c - HD - GD)] = (bf16)acc[m][n][j];
                }
            }
        }
    }
}

// ================================================================ 256x128 3-buffer GEMM (Wo)
// BK=64, 3 bufs x 48KB, 8 waves (4M x 2N, per-wave 64x64), 2 phases/tile (ks0,ks1),
// stage tile t+2 into buf (t+2)%3 (always free), vmcnt(6)+barrier once per tile.
__global__ __launch_bounds__(512) void gemm3b(
    const bf16* __restrict__ A, const bf16* __restrict__ Bt,
    float* __restrict__ C, int N, int K, int nbn)
{
    extern __shared__ char smem[];   // buf b @ b*49152: A 32KB, B @ +32768 (16KB)
    const int tid = threadIdx.x, lane = tid & 63, wave = tid >> 6;
    const int wr = wave >> 1, wc = wave & 1;
    const int l15 = lane & 15, lhi = lane >> 4;
    const int r8 = lane >> 3, c8 = lane & 7;
    const int csw = ((c8 ^ r8) << 3);

    const int nwg = gridDim.x, qq = nwg >> 3;
    const int swz = (blockIdx.x & 7) * qq + (blockIdx.x >> 3);
    const int bm = (swz / nbn) * 256, bn = (swz % nbn) * 128;
    const int NT = K >> 6;

    auto stageA = [&](int buf, int L, int t) {
        int row0 = L * 64 + wave * 8;
        gload16(A + (size_t)(bm + row0 + r8) * K + (t << 6) + csw,
                smem + buf * 49152 + row0 * 128);
    };
    auto stageB = [&](int buf, int L, int t) {
        int row0 = L * 64 + wave * 8;
        gload16(Bt + (size_t)(bn + row0 + r8) * K + (t << 6) + csw,
                smem + buf * 49152 + 32768 + row0 * 128);
    };
    auto rdA = [&](const char* Ab, int ks, bf16x8* af) {
        #pragma unroll
        for (int m = 0; m < 4; ++m) {
            int row = wr * 64 + m * 16 + l15;
            int ch = (ks * 4 + lhi) ^ (l15 & 7);
            af[m] = *reinterpret_cast<const bf16x8*>(Ab + row * 128 + ch * 16);
        }
    };
    auto rdB = [&](const char* Bb, int ks, bf16x8* bfv) {
        #pragma unroll
        for (int n = 0; n < 4; ++n) {
            int row = wc * 64 + n * 16 + l15;
            int ch = (ks * 4 + lhi) ^ (l15 & 7);
            bfv[n] = *reinterpret_cast<const bf16x8*>(Bb + row * 128 + ch * 16);
        }
    };

    f32x4 acc[4][4] = {};

    // prologue: tile0 -> buf0, tile1 -> buf1
    #pragma unroll
    for (int L = 0; L < 4; ++L) stageA(0, L, 0);
    stageB(0, 0, 0); stageB(0, 1, 0);
    #pragma unroll
    for (int L = 0; L < 4; ++L) stageA(1, L, 1);
    stageB(1, 0, 1); stageB(1, 1, 1);
    VMCNT(6);
    BARRIER();

    for (int t = 0; t < NT; ++t) {
        const char* Ab = smem + (t % 3) * 49152;
        const char* Bb = Ab + 32768;
        const int b2 = (t + 2) % 3;
        const int st = (t + 2 < NT) ? t + 2 : NT - 1;
        bf16x8 af[4], bk[4];

        // phase ks0
        rdB(Bb, 0, bk); rdA(Ab, 0, af);
        stageA(b2, 0, st); stageA(b2, 1, st);
        LGKM0();
        __builtin_amdgcn_s_setprio(1);
        #pragma unroll
        for (int m = 0; m < 4; ++m)
            #pragma unroll
            for (int n = 0; n < 4; ++n)
                acc[m][n] = __builtin_amdgcn_mfma_f32_16x16x32_bf16(af[m], bk[n], acc[m][n], 0, 0, 0);
        __builtin_amdgcn_s_setprio(0);

        // phase ks1
        rdB(Bb, 1, bk); rdA(Ab, 1, af);
        stageA(b2, 2, st); stageA(b2, 3, st);
        stageB(b2, 0, st); stageB(b2, 1, st);
        LGKM0();
        __builtin_amdgcn_s_setprio(1);
        #pragma unroll
        for (int m = 0; m < 4; ++m)
            #pragma unroll
            for (int n = 0; n < 4; ++n)
                acc[m][n] = __builtin_amdgcn_mfma_f32_16x16x32_bf16(af[m], bk[n], acc[m][n], 0, 0, 0);
        __builtin_amdgcn_s_setprio(0);

        VMCNT(6);                    // tile t+1 fully landed (this tile's 6 allowed)
        BARRIER();
    }

    #pragma unroll
    for (int m = 0; m < 4; ++m) {
        int r0 = bm + wr * 64 + m * 16 + lhi * 4;
        #pragma unroll
        for (int n = 0; n < 4; ++n) {
            int c = bn + wc * 64 + n * 16 + l15;
            #pragma unroll
            for (int j = 0; j < 4; ++j)
                C[(size_t)(r0 + j) * N + c] = acc[m][n][j];
        }
    }
}

// ---------------------------------------------------------------- fallback GEMM (round-1)
#define BM 128
#define BN 128
#define BK 32
#define LDSK 40

template<bool OUT_BF16>
__global__ __launch_bounds__(256) void gemm_aBf16(
    const bf16* __restrict__ A,
    const float* __restrict__ B0, const float* __restrict__ B1,
    void* __restrict__ C0, void* __restrict__ C1,
    int M, int N, int K)
{
    __shared__ alignas(16) bf16 Al[BM][LDSK];
    __shared__ alignas(16) bf16 Bt[BN][LDSK];

    const float* __restrict__ B = blockIdx.z ? B1 : B0;
    void* __restrict__ C = blockIdx.z ? C1 : C0;

    const int tid  = threadIdx.x;
    const int lane = tid & 63;
    const int wave = tid >> 6;
    const int wm = (wave >> 1) * 64;
    const int wn = (wave & 1) * 64;
    const int bm = blockIdx.y * BM;
    const int bn = blockIdx.x * BN;
    const int l15 = lane & 15;
    const int lhi = lane >> 4;

    f32x4 acc[4][4] = {};

    for (int k0 = 0; k0 < K; k0 += BK) {
        #pragma unroll
        for (int it = 0; it < 2; ++it) {
            int idx = it * 256 + tid;
            int row = idx >> 2;
            int ko  = idx & 3;
            bf16x8 v = *reinterpret_cast<const bf16x8*>(
                A + (size_t)(bm + row) * K + k0 + ko * 8);
            *reinterpret_cast<bf16x8*>(&Al[row][ko * 8]) = v;
        }
        {
            int n = tid & 127;
            int kbase = (tid >> 7) * 8;
            const float* bp = B + (size_t)k0 * N + bn + n;
            #pragma unroll
            for (int half = 0; half < 2; ++half) {
                bf16x8 v;
                #pragma unroll
                for (int j = 0; j < 8; ++j)
                    v[j] = (bf16)bp[(size_t)(half * 16 + kbase + j) * N];
                *reinterpret_cast<bf16x8*>(&Bt[n][half * 16 + kbase]) = v;
            }
        }
        __syncthreads();

        bf16x8 af[4], bfv[4];
        #pragma unroll
        for (int m = 0; m < 4; ++m)
            af[m] = *reinterpret_cast<const bf16x8*>(&Al[wm + m * 16 + l15][lhi * 8]);
        #pragma unroll
        for (int n = 0; n < 4; ++n)
            bfv[n] = *reinterpret_cast<const bf16x8*>(&Bt[wn + n * 16 + l15][lhi * 8]);
        #pragma unroll
        for (int m = 0; m < 4; ++m)
            #pragma unroll
            for (int n = 0; n < 4; ++n)
                acc[m][n] = __builtin_amdgcn_mfma_f32_16x16x32_bf16(
                    af[m], bfv[n], acc[m][n], 0, 0, 0);
        __syncthreads();
    }

    #pragma unroll
    for (int m = 0; m < 4; ++m) {
        int r0 = bm + wm + m * 16 + lhi * 4;
        #pragma unroll
        for (int n = 0; n < 4; ++n) {
            int c = bn + wn + n * 16 + l15;
            #pragma unroll
            for (int j = 0; j < 4; ++j) {
                if constexpr (OUT_BF16)
                    reinterpret_cast<bf16*>(C)[(size_t)(r0 + j) * N + c] = (bf16)acc[m][n][j];
                else
                    reinterpret_cast<float*>(C)[(size_t)(r0 + j) * N + c] = acc[m][n][j];
            }
        }
    }
}

// ---------------------------------------------------------------- flash attention v3
// double-buffered K/V in dynamic LDS (2x32KB + 8KB P), stage(t+1) before compute(t),
// one vmcnt(0)+barrier per tile. 2 blocks/CU.
#define QBLK 64
#define KVBLK 64
#define NQT (S/QBLK)

template<bool MASK>
__device__ __forceinline__ void attn_tile(
    int t0, int q0, int wave, int l15, int lhi,
    const bf16x8* qf, const char* Kl, const char* Vl, char* Plw,
    f32x4* o, float* m_i, float* l_i)
{
    f32x4 sc[4] = {};
    __builtin_amdgcn_s_setprio(1);
    #pragma unroll
    for (int n = 0; n < 4; ++n) {
        int row = n * 16 + l15;
        #pragma unroll
        for (int kk = 0; kk < 4; ++kk) {
            bf16x8 kf = *reinterpret_cast<const bf16x8*>(
                Kl + row * 256 + ((((kk * 4 + lhi)) ^ (l15 & 7)) << 4));
            sc[n] = __builtin_amdgcn_mfma_f32_16x16x32_bf16(qf[kk], kf, sc[n], 0, 0, 0);
        }
    }
    __builtin_amdgcn_s_setprio(0);

    float corr[4];
    #pragma unroll
    for (int j = 0; j < 4; ++j) {
        const int qr = q0 + wave * 16 + lhi * 4 + j;
        float vals[4];
        float mx = -1e30f;
        #pragma unroll
        for (int n = 0; n < 4; ++n) {
            float v = sc[n][j];
            if constexpr (MASK) {
                int t = t0 + n * 16 + l15;
                if (t > qr) v = -1e30f;
            }
            vals[n] = v;
            mx = fmaxf(mx, v);
        }
        #pragma unroll
        for (int ms = 1; ms < 16; ms <<= 1)
            mx = fmaxf(mx, __shfl_xor(mx, ms, 16));
        float mnew = fmaxf(m_i[j], mx);
        float cr = __expf(m_i[j] - mnew);
        float rsum = 0.f;
        #pragma unroll
        for (int n = 0; n < 4; ++n) {
            float p = __expf(vals[n] - mnew);
            rsum += p;
            int r = lhi * 4 + j;
            int off = ((r << 7) + ((n * 16 + l15) << 1)) ^ ((r & 7) << 4);
            *reinterpret_cast<bf16*>(Plw + off) = (bf16)p;
        }
        #pragma unroll
        for (int ms = 1; ms < 16; ms <<= 1)
            rsum += __shfl_xor(rsum, ms, 16);
        l_i[j] = l_i[j] * cr + rsum;
        m_i[j] = mnew;
        corr[j] = cr;
    }

    #pragma unroll
    for (int n = 0; n < 8; ++n)
        #pragma unroll
        for (int j = 0; j < 4; ++j)
            o[n][j] *= corr[j];

    __builtin_amdgcn_s_setprio(1);
    #pragma unroll
    for (int kk = 0; kk < 2; ++kk) {
        bf16x8 pf = *reinterpret_cast<const bf16x8*>(
            Plw + (l15 << 7) + ((((kk * 4 + lhi)) ^ (l15 & 7)) << 4));
        #pragma unroll
        for (int n = 0; n < 8; ++n) {
            int d = n * 16 + l15;
            bf16x8 vf = *reinterpret_cast<const bf16x8*>(
                Vl + (d << 7) + ((((kk * 4 + lhi)) ^ (d & 7)) << 4));
            o[n] = __builtin_amdgcn_mfma_f32_16x16x32_bf16(pf, vf, o[n], 0, 0, 0);
        }
    }
    __builtin_amdgcn_s_setprio(0);
}

__global__ __launch_bounds__(256) void flash_fwd3(
    const bf16* __restrict__ Q, const bf16* __restrict__ Kr,
    const bf16* __restrict__ VtG, bf16* __restrict__ ctx)
{
    extern __shared__ char fsm[];   // buf b: K @ b*32768, V @ b*32768+16384; P @ 65536

    const int tid  = threadIdx.x;
    const int lane = tid & 63;
    const int wave = tid >> 6;
    const int l15 = lane & 15;
    const int lhi = lane >> 4;
    const int bid = blockIdx.x;
    const int qt = (NQT - 1) - (bid >> 5);     // longest tiles dispatched first
    const int h  = bid & 31;
    const int g  = h >> 2;
    const int q0 = qt * QBLK;
    char* Plw = fsm + 65536 + wave * 2048;

    bf16x8 qf[4];
    {
        const bf16* qp = Q + (size_t)(q0 + wave * 16 + l15) * HD + h * DH + lhi * 8;
        #pragma unroll
        for (int kk = 0; kk < 4; ++kk)
            qf[kk] = *reinterpret_cast<const bf16x8*>(qp + kk * 32);
    }

    f32x4 o[8] = {};
    float m_i[4] = { -1e30f, -1e30f, -1e30f, -1e30f };
    float l_i[4] = {};

    auto stage = [&](int t0, int buf) {
        char* Kl = fsm + buf * 32768;
        char* Vl = Kl + 16384;
        #pragma unroll
        for (int t = 0; t < 4; ++t) {
            int ch = wave * 256 + t * 64 + lane;
            {
                int row = ch >> 4, ci = ch & 15;
                gload16(Kr + (size_t)(t0 + row) * GD + g * DH + ((ci ^ (row & 7)) << 3),
                        Kl + (wave * 256 + t * 64) * 16);
            }
            {
                int d = ch >> 3, ci = ch & 7;
                gload16(VtG + (size_t)(g * DH + d) * S + t0 + ((ci ^ (d & 7)) << 3),
                        Vl + (wave * 256 + t * 64) * 16);
            }
        }
    };

    const int nt = qt + 1;
    stage(0, 0);
    VMCNT(0);
    BARRIER();

    for (int it = 0; it < nt; ++it) {
        if (it + 1 < nt) stage((it + 1) * KVBLK, (it + 1) & 1);
        const char* Kl = fsm + (it & 1) * 32768;
        const char* Vl = Kl + 16384;
        if (it == nt - 1)
            attn_tile<true>(it * KVBLK, q0, wave, l15, lhi, qf, Kl, Vl, Plw, o, m_i, l_i);
        else
            attn_tile<false>(it * KVBLK, q0, wave, l15, lhi, qf, Kl, Vl, Plw, o, m_i, l_i);
        VMCNT(0);
        BARRIER();
    }

    #pragma unroll
    for (int n = 0; n < 8; ++n) {
        int c = h * DH + n * 16 + l15;
        #pragma unroll
        for (int j = 0; j < 4; ++j) {
            int r = q0 + wave * 16 + lhi * 4 + j;
            ctx[(size_t)r * HD + c] = (bf16)(o[n][j] / l_i[j]);
        }
    }
}

// ---------------------------------------------------------------- launch
extern "C" void kernel_launch(void* const* d_in, const int* in_sizes, int n_in,
                              void* d_out, int out_size, void* d_ws, size_t ws_size,
                              hipStream_t stream)
{
    const float* x    = (const float*)d_in[0];
    const float* cosT = (const float*)d_in[2];
    const float* sinT = (const float*)d_in[3];
    const float* Wq   = (const float*)d_in[4];
    const float* Wk   = (const float*)d_in[5];
    const float* Wv   = (const float*)d_in[6];
    const float* Wo   = (const float*)d_in[7];
    float* out = (float*)d_out;

    const size_t MB = (size_t)1 << 20;
    char* ws = (char*)d_ws;
    bf16* xb  = (bf16*)ws;                         // 16MB
    bf16* ctx = (bf16*)(ws + 16 * MB);             // 16MB
    bf16* Qb  = (bf16*)d_out;                      // d_out scratch (dead until final GEMM)
    bf16* Kb  = Qb + (size_t)S * HD;
    bf16* Vb  = Kb + (size_t)S * GD;
    bf16* VtG = Vb + (size_t)S * GD;

    const bool fast = ws_size >= 112 * MB;
    const float qscale = 0.08838834764831845f;

    hipFuncSetAttribute(reinterpret_cast<const void*>(&flash_fwd3),
                        hipFuncAttributeMaxDynamicSharedMemorySize, 73728);

    cast_f32_bf16<<<(S * D / 4 + 255) / 256, 256, 0, stream>>>(x, xb, S * D / 4);

    if (fast) {
        bf16* Wqkvt = (bf16*)(ws + 32 * MB);       // [6144][4096] bf16 = 48MB
        bf16* Wot   = (bf16*)(ws + 80 * MB);       // [4096][4096] bf16 = 32MB

        transpose_to_bf16<true><<<dim3(HD / 512, D / 32), 256, 0, stream>>>(Wq, Wqkvt, D, HD);
        transpose_to_bf16<true><<<dim3(GD / 512, D / 32), 256, 0, stream>>>(Wk, Wqkvt + (size_t)HD * D, D, GD);
        transpose_to_bf16<true><<<dim3(GD / 512, D / 32), 256, 0, stream>>>(Wv, Wqkvt + (size_t)(HD + GD) * D, D, GD);
        transpose_to_bf16<true><<<dim3(D / 512, HD / 32), 256, 0, stream>>>(Wo, Wot, HD, D);

        hipFuncSetAttribute(reinterpret_cast<const void*>(&gemm8p<EPI_QKV>),
                            hipFuncAttributeMaxDynamicSharedMemorySize, 131072);
        hipFuncSetAttribute(reinterpret_cast<const void*>(&gemm3b),
                            hipFuncAttributeMaxDynamicSharedMemorySize, 147456);

        // QKV: M=2048, N=6144, K=4096 -> 8x24 = 192 blocks
        gemm8p<EPI_QKV><<<192, 512, 131072, stream>>>(
            xb, Wqkvt, (void*)Qb, Kb, Vb, HD + 2 * GD, D, 24);

        rope_inplace<<<(S * HD / 2 + 255) / 256, 256, 0, stream>>>(Qb, cosT, sinT, HD, S * HD / 2, qscale);
        rope_inplace<<<(S * GD / 2 + 255) / 256, 256, 0, stream>>>(Kb, cosT, sinT, GD, S * GD / 2, 1.0f);

        transpose_to_bf16<false><<<dim3(GD / 512, S / 32), 256, 0, stream>>>(Vb, VtG, S, GD);

        flash_fwd3<<<NQT * H, 256, 73728, stream>>>(Qb, Kb, VtG, ctx);

        // Wo: M=2048, N=4096, K=4096 -> 256x128 tiles, 8x32 = 256 blocks
        gemm3b<<<256, 512, 147456, stream>>>(ctx, Wot, out, D, HD, 32);
    } else {
        gemm_aBf16<true><<<dim3(HD / BN, S / BM, 1), 256, 0, stream>>>(
            xb, Wq, Wq, (void*)Qb, (void*)Qb, S, HD, D);
        gemm_aBf16<true><<<dim3(GD / BN, S / BM, 2), 256, 0, stream>>>(
            xb, Wk, Wv, (void*)Kb, (void*)Vb, S, GD, D);

        rope_inplace<<<(S * HD / 2 + 255) / 256, 256, 0, stream>>>(Qb, cosT, sinT, HD, S * HD / 2, qscale);
        rope_inplace<<<(S * GD / 2 + 255) / 256, 256, 0, stream>>>(Kb, cosT, sinT, GD, S * GD / 2, 1.0f);

        transpose_to_bf16<false><<<dim3(GD / 512, S / 32), 256, 0, stream>>>(Vb, VtG, S, GD);

        flash_fwd3<<<NQT * H, 256, 73728, stream>>>(Qb, Kb, VtG, ctx);

        gemm_aBf16<false><<<dim3(D / BN, S / BM, 1), 256, 0, stream>>>(
            ctx, Wo, Wo, (void*)out, (void*)out, S, D, HD);
    }

    (void)in_sizes; (void)n_in; (void)out_size; (void)ws_size;
}

// Round 5
// 365.367 us; speedup vs baseline: 1.0888x; 1.0888x over previous
//
#include <hip/hip_runtime.h>
#include <hip/hip_bf16.h>
#include <cstdint>
#include <cstddef>

#define S 2048
#define D 4096
#define H 32
#define G 8
#define DH 128
#define HD (H*DH)   // 4096
#define GD (G*DH)   // 1024

typedef __bf16 bf16;
typedef __bf16 bf16x4 __attribute__((ext_vector_type(4)));
typedef __bf16 bf16x8 __attribute__((ext_vector_type(8)));
typedef float f32x4 __attribute__((ext_vector_type(4)));

__device__ __forceinline__ void gload16(const void* g, void* l) {
    __builtin_amdgcn_global_load_lds(
        (const __attribute__((address_space(1))) void*)g,
        (__attribute__((address_space(3))) void*)l, 16, 0, 0);
}

#define FENCE() asm volatile("" ::: "memory")
#define BARRIER() do { FENCE(); __builtin_amdgcn_s_barrier(); FENCE(); } while (0)
#define LGKM0()  do { asm volatile("s_waitcnt lgkmcnt(0)" ::: "memory"); \
                      __builtin_amdgcn_sched_barrier(0); } while (0)
#define VMCNT(n) asm volatile("s_waitcnt vmcnt(" #n ")" ::: "memory")

// ---------------------------------------------------------------- cast x -> bf16
__global__ __launch_bounds__(256) void cast_f32_bf16(const float* __restrict__ in,
                                                     bf16* __restrict__ out, int n4)
{
    int i = blockIdx.x * 256 + threadIdx.x;
    if (i < n4) {
        float4 v = reinterpret_cast<const float4*>(in)[i];
        bf16x4 o = { (bf16)v.x, (bf16)v.y, (bf16)v.z, (bf16)v.w };
        reinterpret_cast<bf16x4*>(out)[i] = o;
    }
}

// ---------------------------------------------------------------- transpose -> bf16
// in [R][C] -> out [C][R] bf16.  64 rows x 256 cols per block.
// lane&7 -> row-octet (so 8 lanes write 128B contiguous in out); tid>>3 -> col-octet.
template<bool IN_F32>
__global__ __launch_bounds__(256) void transpose_to_bf16(
    const void* __restrict__ in, bf16* __restrict__ out, int R, int C)
{
    const int r0 = blockIdx.y * 64 + (threadIdx.x & 7) * 8;
    const int c0 = blockIdx.x * 256 + (threadIdx.x >> 3) * 8;
    bf16 m[8][8];
    #pragma unroll
    for (int j = 0; j < 8; ++j) {
        if constexpr (IN_F32) {
            const float* p = (const float*)in + (size_t)(r0 + j) * C + c0;
            float4 a = *reinterpret_cast<const float4*>(p);
            float4 b = *reinterpret_cast<const float4*>(p + 4);
            m[j][0] = (bf16)a.x; m[j][1] = (bf16)a.y; m[j][2] = (bf16)a.z; m[j][3] = (bf16)a.w;
            m[j][4] = (bf16)b.x; m[j][5] = (bf16)b.y; m[j][6] = (bf16)b.z; m[j][7] = (bf16)b.w;
        } else {
            const bf16* p = (const bf16*)in + (size_t)(r0 + j) * C + c0;
            bf16x8 v = *reinterpret_cast<const bf16x8*>(p);
            #pragma unroll
            for (int i = 0; i < 8; ++i) m[j][i] = v[i];
        }
    }
    #pragma unroll
    for (int i = 0; i < 8; ++i) {
        bf16x8 ov;
        #pragma unroll
        for (int j = 0; j < 8; ++j) ov[j] = m[j][i];
        *reinterpret_cast<bf16x8*>(out + (size_t)(c0 + i) * R + r0) = ov;
    }
}

// ---------------------------------------------------------------- RoPE in-place (+scale)
__global__ __launch_bounds__(256) void rope_inplace(bf16* __restrict__ Y,
                                                    const float* __restrict__ cosT,
                                                    const float* __restrict__ sinT,
                                                    int ncols, int total, float scale)
{
    int idx = blockIdx.x * 256 + threadIdx.x;
    if (idx >= total) return;
    int pairs = ncols >> 1;
    int s = idx / pairs;
    int p = idx - s * pairs;
    int head = p >> 6;
    int d = p & 63;
    size_t base = (size_t)s * ncols + head * DH;
    float c  = cosT[s * DH + d];
    float sn = sinT[s * DH + d];
    float a = (float)Y[base + d];
    float b = (float)Y[base + d + 64];
    Y[base + d]      = (bf16)((a * c - b * sn) * scale);
    Y[base + d + 64] = (bf16)((b * c + a * sn) * scale);
}

// ================================================================ QKV GEMM: 256x192 tile
// C[2048,6144] = A[2048,4096](bf16) @ Bt[6144,4096](bf16).  Grid 8x32 = 256 blocks = 1/CU.
// BK=64, 2 LDS buffers of 56KB (A 32KB + B 24KB). 8 waves 2Mx4N, per-wave 128x48,
// acc[8][3]. 4 phases/tile (mh0ks0, mh0ks1, mh1ks0, mh1ks1), 12 MFMA each; B-frags
// register-cached across mh. Stage units = 8KB (1 gload16/thread). Issue t+1 during t:
// ph1:B0,B1  ph2:B2,A0 (+vmcnt(4): waits t's A1,A3)  ph3:A2,A1  ph4:A3 (+vmcnt(2):
// waits t+1's B0B1B2A0A2). vmcnt AFTER the MFMA cluster so MFMA hides the drain.
__global__ __launch_bounds__(512) void gemm192(
    const bf16* __restrict__ A, const bf16* __restrict__ Bt,
    bf16* __restrict__ Qout, bf16* __restrict__ Kout, bf16* __restrict__ Vout, int K)
{
    extern __shared__ char smem[];   // buf d @ d*57344: A 32KB | B @ +32768 (24KB)
    const int tid = threadIdx.x, lane = tid & 63, wave = tid >> 6;
    const int wr = wave >> 2, wc = wave & 3;
    const int l15 = lane & 15, lhi = lane >> 4;
    const int r8 = lane >> 3, c8 = lane & 7;
    const int csw = ((c8 ^ r8) << 3);          // pre-swizzled source chunk (elems)

    const int bid = blockIdx.x;
    const int swz = (bid & 7) * 32 + (bid >> 3);   // XCD x owns M-panel x
    const int bm = (swz >> 5) * 256, bn = (swz & 31) * 192;
    const int NT = K >> 6;

    auto stA = [&](int buf, int u, int t) {
        gload16(A + (size_t)(bm + u * 64 + wave * 8 + r8) * K + (t << 6) + csw,
                smem + buf * 57344 + u * 8192 + wave * 1024);
    };
    auto stB = [&](int buf, int u, int t) {
        gload16(Bt + (size_t)(bn + u * 64 + wave * 8 + r8) * K + (t << 6) + csw,
                smem + buf * 57344 + 32768 + u * 8192 + wave * 1024);
    };
    auto rdA = [&](const char* Cb, int mh, int ks, bf16x8* af) {
        #pragma unroll
        for (int m = 0; m < 4; ++m) {
            int row = wr * 128 + mh * 64 + m * 16 + l15;
            int ch = (ks * 4 + lhi) ^ (l15 & 7);
            af[m] = *reinterpret_cast<const bf16x8*>(Cb + row * 128 + ch * 16);
        }
    };
    auto rdB = [&](const char* Cb, int ks, bf16x8* bfv) {
        #pragma unroll
        for (int n = 0; n < 3; ++n) {
            int row = wc * 48 + n * 16 + l15;
            int ch = (ks * 4 + lhi) ^ (l15 & 7);
            bfv[n] = *reinterpret_cast<const bf16x8*>(Cb + 32768 + row * 128 + ch * 16);
        }
    };

    f32x4 acc[8][3] = {};

    auto mm = [&](int mh, const bf16x8* af, const bf16x8* bfv) {
        LGKM0();
        __builtin_amdgcn_s_setprio(1);
        #pragma unroll
        for (int m = 0; m < 4; ++m)
            #pragma unroll
            for (int n = 0; n < 3; ++n)
                acc[mh * 4 + m][n] = __builtin_amdgcn_mfma_f32_16x16x32_bf16(
                    af[m], bfv[n], acc[mh * 4 + m][n], 0, 0, 0);
        __builtin_amdgcn_s_setprio(0);
    };

    // prologue: tile0 in steady issue order, leave {A1,A3} outstanding
    stB(0, 0, 0); stB(0, 1, 0); stB(0, 2, 0);
    stA(0, 0, 0); stA(0, 2, 0); stA(0, 1, 0); stA(0, 3, 0);
    VMCNT(2);
    BARRIER();

    for (int t = 0; t < NT; ++t) {
        const char* Cb = smem + (t & 1) * 57344;
        const int nb = (t + 1) & 1;
        const int tn = (t + 1 < NT) ? t + 1 : t;   // clamp: dummy reload, dead buffer
        bf16x8 a4[4], bk0[3], bk1[3];

        // ph1: mh0 ks0
        rdB(Cb, 0, bk0); rdA(Cb, 0, 0, a4);
        stB(nb, 0, tn); stB(nb, 1, tn);
        mm(0, a4, bk0);
        BARRIER();

        // ph2: mh0 ks1
        rdB(Cb, 1, bk1); rdA(Cb, 0, 1, a4);
        stB(nb, 2, tn); stA(nb, 0, tn);
        mm(0, a4, bk1);
        VMCNT(4);                 // waits t's A1,A3 (needed ph3)
        BARRIER();

        // ph3: mh1 ks0
        rdA(Cb, 1, 0, a4);
        stA(nb, 2, tn); stA(nb, 1, tn);
        mm(1, a4, bk0);
        BARRIER();

        // ph4: mh1 ks1
        rdA(Cb, 1, 1, a4);
        stA(nb, 3, tn);
        mm(1, a4, bk1);
        VMCNT(2);                 // waits t+1's B0,B1,B2,A0,A2 (needed its ph1)
        BARRIER();
    }

    #pragma unroll
    for (int m = 0; m < 8; ++m) {
        int r0 = bm + wr * 128 + m * 16 + lhi * 4;
        #pragma unroll
        for (int n = 0; n < 3; ++n) {
            int c = bn + wc * 48 + n * 16 + l15;
            #pragma unroll
            for (int j = 0; j < 4; ++j) {
                bf16 v = (bf16)acc[m][n][j];
                if (c < HD)            Qout[(size_t)(r0 + j) * HD + c] = v;
                else if (c < HD + GD)  Kout[(size_t)(r0 + j) * GD + (c - HD)] = v;
                else                   Vout[(size_t)(r0 + j) * GD + (c - HD - GD)] = v;
            }
        }
    }
}

// ================================================================ 256x128 3-buffer GEMM (Wo)
// BK=64, 3 bufs x 48KB, 8 waves (4M x 2N, per-wave 64x64), 2 phases/tile,
// stage tile t+2 into buf (t+2)%3, vmcnt(6)+barrier once per tile.
__global__ __launch_bounds__(512) void gemm3b(
    const bf16* __restrict__ A, const bf16* __restrict__ Bt,
    float* __restrict__ C, int N, int K, int nbn)
{
    extern __shared__ char smem[];   // buf b @ b*49152: A 32KB, B @ +32768 (16KB)
    const int tid = threadIdx.x, lane = tid & 63, wave = tid >> 6;
    const int wr = wave >> 1, wc = wave & 1;
    const int l15 = lane & 15, lhi = lane >> 4;
    const int r8 = lane >> 3, c8 = lane & 7;
    const int csw = ((c8 ^ r8) << 3);

    const int nwg = gridDim.x, qq = nwg >> 3;
    const int swz = (blockIdx.x & 7) * qq + (blockIdx.x >> 3);
    const int bm = (swz / nbn) * 256, bn = (swz % nbn) * 128;
    const int NT = K >> 6;

    auto stageA = [&](int buf, int L, int t) {
        int row0 = L * 64 + wave * 8;
        gload16(A + (size_t)(bm + row0 + r8) * K + (t << 6) + csw,
                smem + buf * 49152 + row0 * 128);
    };
    auto stageB = [&](int buf, int L, int t) {
        int row0 = L * 64 + wave * 8;
        gload16(Bt + (size_t)(bn + row0 + r8) * K + (t << 6) + csw,
                smem + buf * 49152 + 32768 + row0 * 128);
    };
    auto rdA = [&](const char* Ab, int ks, bf16x8* af) {
        #pragma unroll
        for (int m = 0; m < 4; ++m) {
            int row = wr * 64 + m * 16 + l15;
            int ch = (ks * 4 + lhi) ^ (l15 & 7);
            af[m] = *reinterpret_cast<const bf16x8*>(Ab + row * 128 + ch * 16);
        }
    };
    auto rdB = [&](const char* Bb, int ks, bf16x8* bfv) {
        #pragma unroll
        for (int n = 0; n < 4; ++n) {
            int row = wc * 64 + n * 16 + l15;
            int ch = (ks * 4 + lhi) ^ (l15 & 7);
            bfv[n] = *reinterpret_cast<const bf16x8*>(Bb + row * 128 + ch * 16);
        }
    };

    f32x4 acc[4][4] = {};

    #pragma unroll
    for (int L = 0; L < 4; ++L) stageA(0, L, 0);
    stageB(0, 0, 0); stageB(0, 1, 0);
    #pragma unroll
    for (int L = 0; L < 4; ++L) stageA(1, L, 1);
    stageB(1, 0, 1); stageB(1, 1, 1);
    VMCNT(6);
    BARRIER();

    for (int t = 0; t < NT; ++t) {
        const char* Ab = smem + (t % 3) * 49152;
        const char* Bb = Ab + 32768;
        const int b2 = (t + 2) % 3;
        const int st = (t + 2 < NT) ? t + 2 : NT - 1;
        bf16x8 af[4], bk[4];

        rdB(Bb, 0, bk); rdA(Ab, 0, af);
        stageA(b2, 0, st); stageA(b2, 1, st);
        LGKM0();
        __builtin_amdgcn_s_setprio(1);
        #pragma unroll
        for (int m = 0; m < 4; ++m)
            #pragma unroll
            for (int n = 0; n < 4; ++n)
                acc[m][n] = __builtin_amdgcn_mfma_f32_16x16x32_bf16(af[m], bk[n], acc[m][n], 0, 0, 0);
        __builtin_amdgcn_s_setprio(0);

        rdB(Bb, 1, bk); rdA(Ab, 1, af);
        stageA(b2, 2, st); stageA(b2, 3, st);
        stageB(b2, 0, st); stageB(b2, 1, st);
        LGKM0();
        __builtin_amdgcn_s_setprio(1);
        #pragma unroll
        for (int m = 0; m < 4; ++m)
            #pragma unroll
            for (int n = 0; n < 4; ++n)
                acc[m][n] = __builtin_amdgcn_mfma_f32_16x16x32_bf16(af[m], bk[n], acc[m][n], 0, 0, 0);
        __builtin_amdgcn_s_setprio(0);

        VMCNT(6);
        BARRIER();
    }

    #pragma unroll
    for (int m = 0; m < 4; ++m) {
        int r0 = bm + wr * 64 + m * 16 + lhi * 4;
        #pragma unroll
        for (int n = 0; n < 4; ++n) {
            int c = bn + wc * 64 + n * 16 + l15;
            #pragma unroll
            for (int j = 0; j < 4; ++j)
                C[(size_t)(r0 + j) * N + c] = acc[m][n][j];
        }
    }
}

// ---------------------------------------------------------------- fallback GEMM (round-1)
#define BM 128
#define BN 128
#define BK 32
#define LDSK 40

template<bool OUT_BF16>
__global__ __launch_bounds__(256) void gemm_aBf16(
    const bf16* __restrict__ A,
    const float* __restrict__ B0, const float* __restrict__ B1,
    void* __restrict__ C0, void* __restrict__ C1,
    int M, int N, int K)
{
    __shared__ alignas(16) bf16 Al[BM][LDSK];
    __shared__ alignas(16) bf16 Bt[BN][LDSK];

    const float* __restrict__ B = blockIdx.z ? B1 : B0;
    void* __restrict__ C = blockIdx.z ? C1 : C0;

    const int tid  = threadIdx.x;
    const int lane = tid & 63;
    const int wave = tid >> 6;
    const int wm = (wave >> 1) * 64;
    const int wn = (wave & 1) * 64;
    const int bm = blockIdx.y * BM;
    const int bn = blockIdx.x * BN;
    const int l15 = lane & 15;
    const int lhi = lane >> 4;

    f32x4 acc[4][4] = {};

    for (int k0 = 0; k0 < K; k0 += BK) {
        #pragma unroll
        for (int it = 0; it < 2; ++it) {
            int idx = it * 256 + tid;
            int row = idx >> 2;
            int ko  = idx & 3;
            bf16x8 v = *reinterpret_cast<const bf16x8*>(
                A + (size_t)(bm + row) * K + k0 + ko * 8);
            *reinterpret_cast<bf16x8*>(&Al[row][ko * 8]) = v;
        }
        {
            int n = tid & 127;
            int kbase = (tid >> 7) * 8;
            const float* bp = B + (size_t)k0 * N + bn + n;
            #pragma unroll
            for (int half = 0; half < 2; ++half) {
                bf16x8 v;
                #pragma unroll
                for (int j = 0; j < 8; ++j)
                    v[j] = (bf16)bp[(size_t)(half * 16 + kbase + j) * N];
                *reinterpret_cast<bf16x8*>(&Bt[n][half * 16 + kbase]) = v;
            }
        }
        __syncthreads();

        bf16x8 af[4], bfv[4];
        #pragma unroll
        for (int m = 0; m < 4; ++m)
            af[m] = *reinterpret_cast<const bf16x8*>(&Al[wm + m * 16 + l15][lhi * 8]);
        #pragma unroll
        for (int n = 0; n < 4; ++n)
            bfv[n] = *reinterpret_cast<const bf16x8*>(&Bt[wn + n * 16 + l15][lhi * 8]);
        #pragma unroll
        for (int m = 0; m < 4; ++m)
            #pragma unroll
            for (int n = 0; n < 4; ++n)
                acc[m][n] = __builtin_amdgcn_mfma_f32_16x16x32_bf16(
                    af[m], bfv[n], acc[m][n], 0, 0, 0);
        __syncthreads();
    }

    #pragma unroll
    for (int m = 0; m < 4; ++m) {
        int r0 = bm + wm + m * 16 + lhi * 4;
        #pragma unroll
        for (int n = 0; n < 4; ++n) {
            int c = bn + wn + n * 16 + l15;
            #pragma unroll
            for (int j = 0; j < 4; ++j) {
                if constexpr (OUT_BF16)
                    reinterpret_cast<bf16*>(C)[(size_t)(r0 + j) * N + c] = (bf16)acc[m][n][j];
                else
                    reinterpret_cast<float*>(C)[(size_t)(r0 + j) * N + c] = acc[m][n][j];
            }
        }
    }
}

// ---------------------------------------------------------------- flash attention v3
// double-buffered K/V in dynamic LDS, stage(t+1) before compute(t),
// one vmcnt(0)+barrier per tile. Group g == XCD id for K/V L2 residency.
#define QBLK 64
#define KVBLK 64
#define NQT (S/QBLK)

template<bool MASK>
__device__ __forceinline__ void attn_tile(
    int t0, int q0, int wave, int l15, int lhi,
    const bf16x8* qf, const char* Kl, const char* Vl, char* Plw,
    f32x4* o, float* m_i, float* l_i)
{
    f32x4 sc[4] = {};
    __builtin_amdgcn_s_setprio(1);
    #pragma unroll
    for (int n = 0; n < 4; ++n) {
        int row = n * 16 + l15;
        #pragma unroll
        for (int kk = 0; kk < 4; ++kk) {
            bf16x8 kf = *reinterpret_cast<const bf16x8*>(
                Kl + row * 256 + ((((kk * 4 + lhi)) ^ (l15 & 7)) << 4));
            sc[n] = __builtin_amdgcn_mfma_f32_16x16x32_bf16(qf[kk], kf, sc[n], 0, 0, 0);
        }
    }
    __builtin_amdgcn_s_setprio(0);

    float corr[4];
    #pragma unroll
    for (int j = 0; j < 4; ++j) {
        const int qr = q0 + wave * 16 + lhi * 4 + j;
        float vals[4];
        float mx = -1e30f;
        #pragma unroll
        for (int n = 0; n < 4; ++n) {
            float v = sc[n][j];
            if constexpr (MASK) {
                int t = t0 + n * 16 + l15;
                if (t > qr) v = -1e30f;
            }
            vals[n] = v;
            mx = fmaxf(mx, v);
        }
        #pragma unroll
        for (int ms = 1; ms < 16; ms <<= 1)
            mx = fmaxf(mx, __shfl_xor(mx, ms, 16));
        float mnew = fmaxf(m_i[j], mx);
        float cr = __expf(m_i[j] - mnew);
        float rsum = 0.f;
        #pragma unroll
        for (int n = 0; n < 4; ++n) {
            float p = __expf(vals[n] - mnew);
            rsum += p;
            int r = lhi * 4 + j;
            int off = ((r << 7) + ((n * 16 + l15) << 1)) ^ ((r & 7) << 4);
            *reinterpret_cast<bf16*>(Plw + off) = (bf16)p;
        }
        #pragma unroll
        for (int ms = 1; ms < 16; ms <<= 1)
            rsum += __shfl_xor(rsum, ms, 16);
        l_i[j] = l_i[j] * cr + rsum;
        m_i[j] = mnew;
        corr[j] = cr;
    }

    #pragma unroll
    for (int n = 0; n < 8; ++n)
        #pragma unroll
        for (int j = 0; j < 4; ++j)
            o[n][j] *= corr[j];

    __builtin_amdgcn_s_setprio(1);
    #pragma unroll
    for (int kk = 0; kk < 2; ++kk) {
        bf16x8 pf = *reinterpret_cast<const bf16x8*>(
            Plw + (l15 << 7) + ((((kk * 4 + lhi)) ^ (l15 & 7)) << 4));
        #pragma unroll
        for (int n = 0; n < 8; ++n) {
            int d = n * 16 + l15;
            bf16x8 vf = *reinterpret_cast<const bf16x8*>(
                Vl + (d << 7) + ((((kk * 4 + lhi)) ^ (d & 7)) << 4));
            o[n] = __builtin_amdgcn_mfma_f32_16x16x32_bf16(pf, vf, o[n], 0, 0, 0);
        }
    }
    __builtin_amdgcn_s_setprio(0);
}

__global__ __launch_bounds__(256) void flash_fwd3(
    const bf16* __restrict__ Q, const bf16* __restrict__ Kr,
    const bf16* __restrict__ VtG, bf16* __restrict__ ctx)
{
    extern __shared__ char fsm[];   // buf b: K @ b*32768, V @ b*32768+16384; P @ 65536

    const int tid  = threadIdx.x;
    const int lane = tid & 63;
    const int wave = tid >> 6;
    const int l15 = lane & 15;
    const int lhi = lane >> 4;
    const int bid = blockIdx.x;
    const int qt = (NQT - 1) - (bid >> 5);               // longest tiles first
    const int h  = ((bid & 7) << 2) | ((bid >> 3) & 3);  // g == bid%8 == XCD
    const int g  = h >> 2;
    const int q0 = qt * QBLK;
    char* Plw = fsm + 65536 + wave * 2048;

    bf16x8 qf[4];
    {
        const bf16* qp = Q + (size_t)(q0 + wave * 16 + l15) * HD + h * DH + lhi * 8;
        #pragma unroll
        for (int kk = 0; kk < 4; ++kk)
            qf[kk] = *reinterpret_cast<const bf16x8*>(qp + kk * 32);
    }

    f32x4 o[8] = {};
    float m_i[4] = { -1e30f, -1e30f, -1e30f, -1e30f };
    float l_i[4] = {};

    auto stage = [&](int t0, int buf) {
        char* Kl = fsm + buf * 32768;
        char* Vl = Kl + 16384;
        #pragma unroll
        for (int t = 0; t < 4; ++t) {
            int ch = wave * 256 + t * 64 + lane;
            {
                int row = ch >> 4, ci = ch & 15;
                gload16(Kr + (size_t)(t0 + row) * GD + g * DH + ((ci ^ (row & 7)) << 3),
                        Kl + (wave * 256 + t * 64) * 16);
            }
            {
                int d = ch >> 3, ci = ch & 7;
                gload16(VtG + (size_t)(g * DH + d) * S + t0 + ((ci ^ (d & 7)) << 3),
                        Vl + (wave * 256 + t * 64) * 16);
            }
        }
    };

    const int nt = qt + 1;
    stage(0, 0);
    VMCNT(0);
    BARRIER();

    for (int it = 0; it < nt; ++it) {
        if (it + 1 < nt) stage((it + 1) * KVBLK, (it + 1) & 1);
        const char* Kl = fsm + (it & 1) * 32768;
        const char* Vl = Kl + 16384;
        if (it == nt - 1)
            attn_tile<true>(it * KVBLK, q0, wave, l15, lhi, qf, Kl, Vl, Plw, o, m_i, l_i);
        else
            attn_tile<false>(it * KVBLK, q0, wave, l15, lhi, qf, Kl, Vl, Plw, o, m_i, l_i);
        VMCNT(0);
        BARRIER();
    }

    #pragma unroll
    for (int n = 0; n < 8; ++n) {
        int c = h * DH + n * 16 + l15;
        #pragma unroll
        for (int j = 0; j < 4; ++j) {
            int r = q0 + wave * 16 + lhi * 4 + j;
            ctx[(size_t)r * HD + c] = (bf16)(o[n][j] / l_i[j]);
        }
    }
}

// ---------------------------------------------------------------- launch
extern "C" void kernel_launch(void* const* d_in, const int* in_sizes, int n_in,
                              void* d_out, int out_size, void* d_ws, size_t ws_size,
                              hipStream_t stream)
{
    const float* x    = (const float*)d_in[0];
    const float* cosT = (const float*)d_in[2];
    const float* sinT = (const float*)d_in[3];
    const float* Wq   = (const float*)d_in[4];
    const float* Wk   = (const float*)d_in[5];
    const float* Wv   = (const float*)d_in[6];
    const float* Wo   = (const float*)d_in[7];
    float* out = (float*)d_out;

    const size_t MB = (size_t)1 << 20;
    char* ws = (char*)d_ws;
    bf16* xb  = (bf16*)ws;                         // 16MB
    bf16* ctx = (bf16*)(ws + 16 * MB);             // 16MB
    bf16* Qb  = (bf16*)d_out;                      // d_out scratch (dead until final GEMM)
    bf16* Kb  = Qb + (size_t)S * HD;
    bf16* Vb  = Kb + (size_t)S * GD;
    bf16* VtG = Vb + (size_t)S * GD;

    const bool fast = ws_size >= 112 * MB;
    const float qscale = 0.08838834764831845f;

    hipFuncSetAttribute(reinterpret_cast<const void*>(&flash_fwd3),
                        hipFuncAttributeMaxDynamicSharedMemorySize, 73728);

    cast_f32_bf16<<<(S * D / 4 + 255) / 256, 256, 0, stream>>>(x, xb, S * D / 4);

    if (fast) {
        bf16* Wqkvt = (bf16*)(ws + 32 * MB);       // [6144][4096] bf16 = 48MB
        bf16* Wot   = (bf16*)(ws + 80 * MB);       // [4096][4096] bf16 = 32MB

        transpose_to_bf16<true><<<dim3(HD / 256, D / 64), 256, 0, stream>>>(Wq, Wqkvt, D, HD);
        transpose_to_bf16<true><<<dim3(GD / 256, D / 64), 256, 0, stream>>>(Wk, Wqkvt + (size_t)HD * D, D, GD);
        transpose_to_bf16<true><<<dim3(GD / 256, D / 64), 256, 0, stream>>>(Wv, Wqkvt + (size_t)(HD + GD) * D, D, GD);
        transpose_to_bf16<true><<<dim3(D / 256, HD / 64), 256, 0, stream>>>(Wo, Wot, HD, D);

        hipFuncSetAttribute(reinterpret_cast<const void*>(&gemm192),
                            hipFuncAttributeMaxDynamicSharedMemorySize, 114688);
        hipFuncSetAttribute(reinterpret_cast<const void*>(&gemm3b),
                            hipFuncAttributeMaxDynamicSharedMemorySize, 147456);

        // QKV: 256x192 tiles -> 8x32 = 256 blocks = 1/CU
        gemm192<<<256, 512, 114688, stream>>>(xb, Wqkvt, Qb, Kb, Vb, D);

        rope_inplace<<<(S * HD / 2 + 255) / 256, 256, 0, stream>>>(Qb, cosT, sinT, HD, S * HD / 2, qscale);
        rope_inplace<<<(S * GD / 2 + 255) / 256, 256, 0, stream>>>(Kb, cosT, sinT, GD, S * GD / 2, 1.0f);

        transpose_to_bf16<false><<<dim3(GD / 256, S / 64), 256, 0, stream>>>(Vb, VtG, S, GD);

        flash_fwd3<<<NQT * H, 256, 73728, stream>>>(Qb, Kb, VtG, ctx);

        // Wo: 256x128 tiles, 8x32 = 256 blocks
        gemm3b<<<256, 512, 147456, stream>>>(ctx, Wot, out, D, HD, 32);
    } else {
        gemm_aBf16<true><<<dim3(HD / BN, S / BM, 1), 256, 0, stream>>>(
            xb, Wq, Wq, (void*)Qb, (void*)Qb, S, HD, D);
        gemm_aBf16<true><<<dim3(GD / BN, S / BM, 2), 256, 0, stream>>>(
            xb, Wk, Wv, (void*)Kb, (void*)Vb, S, GD, D);

        rope_inplace<<<(S * HD / 2 + 255) / 256, 256, 0, stream>>>(Qb, cosT, sinT, HD, S * HD / 2, qscale);
        rope_inplace<<<(S * GD / 2 + 255) / 256, 256, 0, stream>>>(Kb, cosT, sinT, GD, S * GD / 2, 1.0f);

        transpose_to_bf16<false><<<dim3(GD / 256, S / 64), 256, 0, stream>>>(Vb, VtG, S, GD);

        flash_fwd3<<<NQT * H, 256, 73728, stream>>>(Qb, Kb, VtG, ctx);

        gemm_aBf16<false><<<dim3(D / BN, S / BM, 1), 256, 0, stream>>>(
            ctx, Wo, Wo, (void*)out, (void*)out, S, D, HD);
    }

    (void)in_sizes; (void)n_in; (void)out_size; (void)ws_size;
}